// Round 7
// baseline (285.642 us; speedup 1.0000x reference)
//
#include <hip/hip_runtime.h>
#include <stdint.h>

#define HW   16384          // 128*128
#define NPIX 131072         // 8 * HW

typedef __attribute__((ext_vector_type(8)))  _Float16 half8;
typedef __attribute__((ext_vector_type(16))) float    f32x16;

__device__ __forceinline__ float sigm(float x) { return 1.f / (1.f + __expf(-x)); }

// ---------------------------------------------------------------------------
// R13: test the DRAM-granule hypothesis (H1).
//   R12 post-mortem: occupancy 35.6->65% with time FLAT (78.8->80.5us), VALU/
//   MFMA/HBM all unchanged -> latency/TLP theory REFUTED. Everything idle +
//   time invariant to concurrency = throughput ceiling in the memory path for
//   this pattern. Shared feature of R0/R7/R11/R12 (~79-100us wall): hf read in
//   512B-per-channel granules at 64KB stride (128px/block) -> DRAM row
//   re-activate per 512B, scattered line order. Fills do 6.8 TB/s, spill
//   traffic 2.6 TB/s -> system is fine, pattern is not.
//   Fix (single variable): 512 px/block, 1024 thr = 16 waves, grid 256.
//   Per-wave job IDENTICAL to R7 (32px x K256, same loop, same regs); waves/CU
//   still 16. Only change: per-channel contiguity 512B -> 2KB (full DRAM row
//   consumed per visit). sacc[22][512] = 45KB LDS. Epi unchanged, role=tid>>9.
// ---------------------------------------------------------------------------

// Pack padded 32x256 weight matrix (rows 0..19 = pdp_w1 hf-cols, row 20 =
// dU_aw[0:256], row 21 = dL_aw[0:256], rows 22..31 = 0) into lane-ordered
// split-f16 fragments: apack[s*512 + l*8 + j], s = K-step of 16.
__global__ __launch_bounds__(256) void prep_apack(
    const float* __restrict__ pdp_w1, const float* __restrict__ dU_aw,
    const float* __restrict__ dL_aw, _Float16* __restrict__ apack)
{
    int idx = blockIdx.x * 256 + threadIdx.x;      // [0, 8192)
    int s = idx >> 9, rem = idx & 511, l = rem >> 3, j = rem & 7;
    int o = l & 31, kh = l >> 5;
    int k = s * 16 + kh * 8 + j;
    float wv = 0.f;
    if (o < 20)       wv = pdp_w1[o * 276 + k];
    else if (o == 20) wv = dU_aw[k];
    else if (o == 21) wv = dL_aw[k];
    _Float16 h = (_Float16)wv;
    apack[idx]        = h;                          // A_hi
    apack[8192 + idx] = (_Float16)(wv - (float)h);  // A_lo (residual)
}

__global__ __launch_bounds__(1024, 4) void half_graph_fused(
    const float* __restrict__ hf,  const float* __restrict__ xhu, const float* __restrict__ xhl,
    const float* __restrict__ xfg, const float* __restrict__ xpg,
    const float* __restrict__ pdp_w1, const float* __restrict__ pdp_w2,
    const float* __restrict__ att_w,  const float* __restrict__ att_b,
    const float* __restrict__ cU_aw, const float* __restrict__ cU_ab, const float* __restrict__ cU_w,
    const float* __restrict__ cL_aw, const float* __restrict__ cL_ab, const float* __restrict__ cL_w,
    const float* __restrict__ dU_aw, const float* __restrict__ dU_ab, const float* __restrict__ dU_w,
    const float* __restrict__ dL_aw, const float* __restrict__ dL_ab, const float* __restrict__ dL_w,
    const float* __restrict__ uU_gw, const float* __restrict__ uU_gb, const float* __restrict__ uU_cw,
    const float* __restrict__ uL_gw, const float* __restrict__ uL_gb, const float* __restrict__ uL_cw,
    const _Float16* __restrict__ apack,
    float* __restrict__ out)
{
    const int tid    = threadIdx.x;
    const int pxbase = blockIdx.x * 512;     // 512 px/block (512 | 16384)
    const int n      = pxbase >> 14;
    const int hwbase = pxbase & 16383;

    __shared__ float sacc[22][512];          // 45 KB

    // ---- GEMM: 16 waves; wave w = px tile w (32 px), full K=256 -----------
    {
        const int l   = tid & 63;
        const int w   = tid >> 6;            // px tile [0,16)
        const int col = l & 31;
        const int kh  = l >> 5;
        const float* bp = hf + ((size_t)n * 256 + kh * 8) * HW
                             + hwbase + w * 32 + col;
        const half8* ahp = (const half8*)apack + l;   // [16 steps][64 lanes]
        const half8* alp = ahp + 1024;
        f32x16 acc = {};
        #pragma unroll 2
        for (int s = 0; s < 16; ++s) {
            half8 A_h = ahp[s * 64];
            half8 A_l = alp[s * 64];
            float x[8];
            #pragma unroll
            for (int j = 0; j < 8; ++j) x[j] = bp[(size_t)(s * 16 + j) * HW];  // coalesced
            half8 B_h, B_l;
            #pragma unroll
            for (int j = 0; j < 8; ++j) {          // split f32 -> f16 hi + lo
                _Float16 h = (_Float16)x[j];
                B_h[j] = h;
                B_l[j] = (_Float16)(x[j] - (float)h);
            }
            acc = __builtin_amdgcn_mfma_f32_32x32x16_f16(A_h, B_h, acc, 0, 0, 0);
            acc = __builtin_amdgcn_mfma_f32_32x32x16_f16(A_h, B_l, acc, 0, 0, 0);
            acc = __builtin_amdgcn_mfma_f32_32x32x16_f16(A_l, B_h, acc, 0, 0, 0);
        }
        // C/D: col=lane&31, row=(reg&3)+8*(reg>>2)+4*(lane>>5)  [R7-verified]
        const int ccol = w * 32 + col;
        #pragma unroll
        for (int reg = 0; reg < 12; ++reg) {
            const int r = (reg & 3) + 8 * (reg >> 2) + 4 * kh;
            if (r < 22) sacc[r][ccol] = acc[reg];
        }
    }

    // per-pixel small vectors: issue before the barrier
    const int q    = tid & 511;              // pixel within block
    const int role = tid >> 9;               // waves 0-7: U, waves 8-15: L
    const int hw   = hwbase + q;
    const int vb   = n * 10 * HW + hw;
    float xu[10], xl[10], xv[10];
    #pragma unroll
    for (int i = 0; i < 10; ++i) xu[i] = xhu[vb + i * HW];
    #pragma unroll
    for (int i = 0; i < 10; ++i) xl[i] = xhl[vb + i * HW];
    #pragma unroll
    for (int i = 0; i < 10; ++i) xv[i] = xfg[vb + i * HW];

    __syncthreads();

    // gates (both halves need both)
    float au_s = att_b[0], al_s = att_b[1];
    #pragma unroll
    for (int i = 0; i < 10; ++i) {
        au_s = fmaf(att_w[i],      xu[i], au_s);
        al_s = fmaf(att_w[10 + i], xl[i], al_s);
    }
    const float au = sigm(au_s), al = sigm(al_s);

    if (role == 0) {
        // ------------------------------ U half ------------------------------
        float tt[10];                        // t rows 10..19 (feed dp_l)
        #pragma unroll
        for (int o = 0; o < 10; ++o) {
            const float* wr = pdp_w1 + (10 + o) * 276;
            float s = sacc[10 + o][q];
            #pragma unroll
            for (int i = 0; i < 10; ++i) s = fmaf(wr[256 + i], xu[i], s);
            #pragma unroll
            for (int i = 0; i < 10; ++i) s = fmaf(wr[266 + i], xl[i], s);
            tt[o] = fmaxf(s, 0.f);
        }
        float dpl[10];
        #pragma unroll
        for (int o = 0; o < 10; ++o) {
            float s = 0.f;
            #pragma unroll
            for (int i = 0; i < 10; ++i) s = fmaf(pdp_w2[(10 + o) * 10 + i], tt[i], s);
            dpl[o] = fmaxf(s, 0.f);
        }
        float su = sacc[20][q] + dU_ab[0];
        #pragma unroll
        for (int i = 0; i < 10; ++i) su = fmaf(dU_aw[256 + i], xv[i], su);
        #pragma unroll
        for (int i = 0; i < 10; ++i) su = fmaf(dU_aw[266 + i], xu[i], su);
        const float attU = sigm(su);
        float xfh[10];
        #pragma unroll
        for (int o = 0; o < 10; ++o) {
            float a = 0.f;
            #pragma unroll
            for (int i = 0; i < 10; ++i) a = fmaf(dU_w[o * 10 + i], xv[i], a);
            xfh[o] = fmaxf(attU * a, 0.f);
        }
        float msg[10];
        #pragma unroll
        for (int i = 0; i < 10; ++i) msg[i] = 0.f;
        #pragma unroll
        for (int pp = 0; pp < 4; ++pp) {
            const float* xq = xpg + (size_t)(pp * 8 + n) * 10 * HW + hw;
            float v[10];
            #pragma unroll
            for (int i = 0; i < 10; ++i) v[i] = xq[i * HW];
            float s = cU_ab[pp];
            #pragma unroll
            for (int i = 0; i < 10; ++i) s = fmaf(cU_aw[pp * 10 + i], v[i], s);
            float ca = sigm(s);
            #pragma unroll
            for (int i = 0; i < 10; ++i) msg[i] = fmaf(ca, v[i], msg[i]);
        }
        float m[10];
        #pragma unroll
        for (int o = 0; o < 10; ++o) {
            float s = 0.f;
            #pragma unroll
            for (int i = 0; i < 10; ++i) s = fmaf(cU_w[o * 20 + i],      xu[i],  s);
            #pragma unroll
            for (int i = 0; i < 10; ++i) s = fmaf(cU_w[o * 20 + 10 + i], msg[i], s);
            m[o] = fmaxf(s, 0.f) + fmaf(dpl[o], al, xu[o] * au) + xfh[o];
        }
        #pragma unroll
        for (int o = 0; o < 10; ++o) {
            float gs = uU_gb[o], cs = 0.f;
            #pragma unroll
            for (int i = 0; i < 10; ++i) {
                gs = fmaf(uU_gw[o * 20 + i], xu[i], gs);
                cs = fmaf(uU_cw[o * 20 + i], xu[i], cs);
            }
            #pragma unroll
            for (int i = 0; i < 10; ++i) {
                gs = fmaf(uU_gw[o * 20 + 10 + i], m[i], gs);
                cs = fmaf(uU_cw[o * 20 + 10 + i], m[i], cs);
            }
            float g = sigm(gs), cd = fmaxf(cs, 0.f);
            out[vb + o * HW] = xu[o] * (1.f - g) + cd * g;
        }
        out[2621440 + n * HW + hw] = attU;
    } else {
        // ------------------------------ L half ------------------------------
        float tt[10];                        // t rows 0..9 (feed dp_u)
        #pragma unroll
        for (int o = 0; o < 10; ++o) {
            const float* wr = pdp_w1 + o * 276;
            float s = sacc[o][q];
            #pragma unroll
            for (int i = 0; i < 10; ++i) s = fmaf(wr[256 + i], xu[i], s);
            #pragma unroll
            for (int i = 0; i < 10; ++i) s = fmaf(wr[266 + i], xl[i], s);
            tt[o] = fmaxf(s, 0.f);
        }
        float dpu[10];
        #pragma unroll
        for (int o = 0; o < 10; ++o) {
            float s = 0.f;
            #pragma unroll
            for (int i = 0; i < 10; ++i) s = fmaf(pdp_w2[o * 10 + i], tt[i], s);
            dpu[o] = fmaxf(s, 0.f);
        }
        float sl = sacc[21][q] + dL_ab[0];
        #pragma unroll
        for (int i = 0; i < 10; ++i) sl = fmaf(dL_aw[256 + i], xv[i], sl);
        #pragma unroll
        for (int i = 0; i < 10; ++i) sl = fmaf(dL_aw[266 + i], xl[i], sl);
        const float attL = sigm(sl);
        float xfh[10];
        #pragma unroll
        for (int o = 0; o < 10; ++o) {
            float a = 0.f;
            #pragma unroll
            for (int i = 0; i < 10; ++i) a = fmaf(dL_w[o * 10 + i], xv[i], a);
            xfh[o] = fmaxf(attL * a, 0.f);
        }
        float msg[10];
        #pragma unroll
        for (int i = 0; i < 10; ++i) msg[i] = 0.f;
        #pragma unroll
        for (int pp = 0; pp < 2; ++pp) {
            const float* xq = xpg + (size_t)((pp + 4) * 8 + n) * 10 * HW + hw;
            float v[10];
            #pragma unroll
            for (int i = 0; i < 10; ++i) v[i] = xq[i * HW];
            float s = cL_ab[pp];
            #pragma unroll
            for (int i = 0; i < 10; ++i) s = fmaf(cL_aw[pp * 10 + i], v[i], s);
            float ca = sigm(s);
            #pragma unroll
            for (int i = 0; i < 10; ++i) msg[i] = fmaf(ca, v[i], msg[i]);
        }
        float m[10];
        #pragma unroll
        for (int o = 0; o < 10; ++o) {
            float s = 0.f;
            #pragma unroll
            for (int i = 0; i < 10; ++i) s = fmaf(cL_w[o * 20 + i],      xl[i],  s);
            #pragma unroll
            for (int i = 0; i < 10; ++i) s = fmaf(cL_w[o * 20 + 10 + i], msg[i], s);
            m[o] = fmaxf(s, 0.f) + fmaf(dpu[o], au, xl[o] * al) + xfh[o];
        }
        #pragma unroll
        for (int o = 0; o < 10; ++o) {
            float gs = uL_gb[o], cs = 0.f;
            #pragma unroll
            for (int i = 0; i < 10; ++i) {
                gs = fmaf(uL_gw[o * 20 + i], xl[i], gs);
                cs = fmaf(uL_cw[o * 20 + i], xl[i], cs);
            }
            #pragma unroll
            for (int i = 0; i < 10; ++i) {
                gs = fmaf(uL_gw[o * 20 + 10 + i], m[i], gs);
                cs = fmaf(uL_cw[o * 20 + 10 + i], m[i], cs);
            }
            float g = sigm(gs), cd = fmaxf(cs, 0.f);
            out[1310720 + vb + o * HW] = xl[o] * (1.f - g) + cd * g;
        }
        out[2752512 + n * HW + hw] = attL;
    }
}

extern "C" void kernel_launch(void* const* d_in, const int* in_sizes, int n_in,
                              void* d_out, int out_size, void* d_ws, size_t ws_size,
                              hipStream_t stream) {
    (void)in_sizes; (void)n_in; (void)out_size; (void)ws_size;
    const float* hf   = (const float*)d_in[0];
    const float* xhu  = (const float*)d_in[1];
    const float* xhl  = (const float*)d_in[2];
    const float* xfg  = (const float*)d_in[3];
    const float* xpg  = (const float*)d_in[4];
    const float* w1   = (const float*)d_in[5];
    const float* w2   = (const float*)d_in[6];
    const float* aw   = (const float*)d_in[7];
    const float* ab   = (const float*)d_in[8];
    const float* cUaw = (const float*)d_in[9];
    const float* cUab = (const float*)d_in[10];
    const float* cUw  = (const float*)d_in[11];
    const float* cLaw = (const float*)d_in[12];
    const float* cLab = (const float*)d_in[13];
    const float* cLw  = (const float*)d_in[14];
    const float* dUaw = (const float*)d_in[15];
    const float* dUab = (const float*)d_in[16];
    const float* dUw  = (const float*)d_in[17];
    const float* dLaw = (const float*)d_in[18];
    const float* dLab = (const float*)d_in[19];
    const float* dLw  = (const float*)d_in[20];
    const float* uUgw = (const float*)d_in[21];
    const float* uUgb = (const float*)d_in[22];
    const float* uUcw = (const float*)d_in[23];
    const float* uLgw = (const float*)d_in[24];
    const float* uLgb = (const float*)d_in[25];
    const float* uLcw = (const float*)d_in[26];

    _Float16* apack = (_Float16*)d_ws;       // 32 KB: [16][64][8] hi + lo

    hipLaunchKernelGGL(prep_apack, dim3(32), dim3(256), 0, stream,
                       w1, dUaw, dLaw, apack);
    hipLaunchKernelGGL(half_graph_fused, dim3(256), dim3(1024), 0, stream,
        hf, xhu, xhl, xfg, xpg, w1, w2, aw, ab,
        cUaw, cUab, cUw, cLaw, cLab, cLw,
        dUaw, dUab, dUw, dLaw, dLab, dLw,
        uUgw, uUgb, uUcw, uLgw, uLgb, uLcw,
        (const _Float16*)apack,
        (float*)d_out);
}

// Round 8
// 276.130 us; speedup vs baseline: 1.0344x; 1.0344x over previous
//
#include <hip/hip_runtime.h>
#include <stdint.h>

#define HW   16384          // 128*128
#define NPIX 131072         // 8 * HW

typedef __attribute__((ext_vector_type(4)))  float    f32x4;
typedef __attribute__((ext_vector_type(8)))  _Float16 half8;
typedef __attribute__((ext_vector_type(16))) float    f32x16;

__device__ __forceinline__ float sigm(float x) { return 1.f / (1.f + __expf(-x)); }

// ---------------------------------------------------------------------------
// R14: raise BYTES PER MEMORY REQUEST on the hf stream (134 MB, 70% of traffic).
//   R12 (2x waves) and R13 (4x contiguity) both null at ~80us, 1.28 TB/s,
//   all pipes idle -> per-CU outstanding-REQUEST capacity is the full resource
//   (2.08 B/cy/CU x ~480cy ~ only a few 256B requests in flight). Evidence the
//   system has headroom: fills 6.8 TB/s; R8 (same hf loads + 750MB of 16B/lane
//   scratch traffic) sustained 2.6 TB/s. Lever: per-lane dwordx4.
//   Fix: stage hf through LDS. Block = 256 px, 512 thr, grid 512. K walked in
//   32-ch chunks; staging = per-lane float4, one wave-instr = 1 KB contiguous
//   channel row (m13 pattern). Reg-prefetch next chunk under MFMA. LDS 54 KB
//   (32 stage + 22 sacc) -> 2 blocks/CU: one block's scalar epi overlaps the
//   other's streaming stage. MFMA math, A-frags, sacc layout, epi: unchanged.
// ---------------------------------------------------------------------------

// Pack padded 32x256 weight matrix (rows 0..19 = pdp_w1 hf-cols, row 20 =
// dU_aw[0:256], row 21 = dL_aw[0:256], rows 22..31 = 0) into lane-ordered
// split-f16 fragments: apack[s*512 + l*8 + j], s = K-step of 16.
__global__ __launch_bounds__(256) void prep_apack(
    const float* __restrict__ pdp_w1, const float* __restrict__ dU_aw,
    const float* __restrict__ dL_aw, _Float16* __restrict__ apack)
{
    int idx = blockIdx.x * 256 + threadIdx.x;      // [0, 8192)
    int s = idx >> 9, rem = idx & 511, l = rem >> 3, j = rem & 7;
    int o = l & 31, kh = l >> 5;
    int k = s * 16 + kh * 8 + j;
    float wv = 0.f;
    if (o < 20)       wv = pdp_w1[o * 276 + k];
    else if (o == 20) wv = dU_aw[k];
    else if (o == 21) wv = dL_aw[k];
    _Float16 h = (_Float16)wv;
    apack[idx]        = h;                          // A_hi
    apack[8192 + idx] = (_Float16)(wv - (float)h);  // A_lo (residual)
}

__global__ __launch_bounds__(512, 4) void half_graph_fused(
    const float* __restrict__ hf,  const float* __restrict__ xhu, const float* __restrict__ xhl,
    const float* __restrict__ xfg, const float* __restrict__ xpg,
    const float* __restrict__ pdp_w1, const float* __restrict__ pdp_w2,
    const float* __restrict__ att_w,  const float* __restrict__ att_b,
    const float* __restrict__ cU_aw, const float* __restrict__ cU_ab, const float* __restrict__ cU_w,
    const float* __restrict__ cL_aw, const float* __restrict__ cL_ab, const float* __restrict__ cL_w,
    const float* __restrict__ dU_aw, const float* __restrict__ dU_ab, const float* __restrict__ dU_w,
    const float* __restrict__ dL_aw, const float* __restrict__ dL_ab, const float* __restrict__ dL_w,
    const float* __restrict__ uU_gw, const float* __restrict__ uU_gb, const float* __restrict__ uU_cw,
    const float* __restrict__ uL_gw, const float* __restrict__ uL_gb, const float* __restrict__ uL_cw,
    const _Float16* __restrict__ apack,
    float* __restrict__ out)
{
    const int tid    = threadIdx.x;
    const int pxbase = blockIdx.x * 256;     // 256 px/block (256 | 16384)
    const int n      = pxbase >> 14;
    const int hwbase = pxbase & 16383;

    __shared__ float lstage[32][256];        // 32 KB  (one 32-ch K-chunk)
    __shared__ float sacc[22][256];          // 22 KB

    // ---- GEMM: 8 waves; wave w = px tile w*32; K in 8 chunks of 32 ch -----
    {
        const int l   = tid & 63;
        const int w   = tid >> 6;            // px tile [0,8)
        const int col = l & 31;
        const int kh  = l >> 5;
        const half8* ahp = (const half8*)apack + l;   // [16 steps][64 lanes]
        const half8* alp = ahp + 1024;
        const float* hfb = hf + (size_t)n * 256 * HW + hwbase;

        f32x16 acc = {};
        f32x4 pf[4];
        // prefetch chunk 0: thread covers 4 float4s; one wave-instr = 1 KB
        // contiguous (64 lanes x 16B inside one 256px channel row pair)
        #pragma unroll
        for (int i = 0; i < 4; ++i) {
            int fid = i * 512 + tid;         // [0, 2048)
            int ch = fid >> 6, f = fid & 63;
            pf[i] = *(const f32x4*)&hfb[(size_t)ch * HW + f * 4];
        }
        for (int c = 0; c < 8; ++c) {
            // write prefetched chunk c to LDS
            #pragma unroll
            for (int i = 0; i < 4; ++i) {
                int fid = i * 512 + tid;
                int ch = fid >> 6, f = fid & 63;
                *(f32x4*)&lstage[ch][f * 4] = pf[i];
            }
            __syncthreads();
            // issue chunk c+1 global loads; latency hides under MFMA below
            if (c < 7) {
                const float* src = hfb + (size_t)(c + 1) * 32 * HW;
                #pragma unroll
                for (int i = 0; i < 4; ++i) {
                    int fid = i * 512 + tid;
                    int ch = fid >> 6, f = fid & 63;
                    pf[i] = *(const f32x4*)&src[(size_t)ch * HW + f * 4];
                }
            }
            // consume chunk c: 2 K-steps of 16 ch
            #pragma unroll
            for (int s = 0; s < 2; ++s) {
                const int S = c * 2 + s;
                half8 A_h = ahp[S * 64];
                half8 A_l = alp[S * 64];
                float x[8];
                #pragma unroll
                for (int j = 0; j < 8; ++j)
                    x[j] = lstage[s * 16 + kh * 8 + j][w * 32 + col];  // 2-way = free
                half8 B_h, B_l;
                #pragma unroll
                for (int j = 0; j < 8; ++j) {      // split f32 -> f16 hi + lo
                    _Float16 h = (_Float16)x[j];
                    B_h[j] = h;
                    B_l[j] = (_Float16)(x[j] - (float)h);
                }
                acc = __builtin_amdgcn_mfma_f32_32x32x16_f16(A_h, B_h, acc, 0, 0, 0);
                acc = __builtin_amdgcn_mfma_f32_32x32x16_f16(A_h, B_l, acc, 0, 0, 0);
                acc = __builtin_amdgcn_mfma_f32_32x32x16_f16(A_l, B_h, acc, 0, 0, 0);
            }
            __syncthreads();                 // lstage free for chunk c+1
        }
        // C/D: col=lane&31, row=(reg&3)+8*(reg>>2)+4*(lane>>5)  [R7-verified]
        const int ccol = w * 32 + col;
        #pragma unroll
        for (int reg = 0; reg < 12; ++reg) {
            const int r = (reg & 3) + 8 * (reg >> 2) + 4 * kh;
            if (r < 22) sacc[r][ccol] = acc[reg];
        }
    }

    // per-pixel small vectors: issue before the barrier
    const int q    = tid & 255;              // pixel within block
    const int role = tid >> 8;               // waves 0-3: U, waves 4-7: L
    const int hw   = hwbase + q;
    const int vb   = n * 10 * HW + hw;
    float xu[10], xl[10], xv[10];
    #pragma unroll
    for (int i = 0; i < 10; ++i) xu[i] = xhu[vb + i * HW];
    #pragma unroll
    for (int i = 0; i < 10; ++i) xl[i] = xhl[vb + i * HW];
    #pragma unroll
    for (int i = 0; i < 10; ++i) xv[i] = xfg[vb + i * HW];

    __syncthreads();

    // gates (both halves need both)
    float au_s = att_b[0], al_s = att_b[1];
    #pragma unroll
    for (int i = 0; i < 10; ++i) {
        au_s = fmaf(att_w[i],      xu[i], au_s);
        al_s = fmaf(att_w[10 + i], xl[i], al_s);
    }
    const float au = sigm(au_s), al = sigm(al_s);

    if (role == 0) {
        // ------------------------------ U half ------------------------------
        float tt[10];                        // t rows 10..19 (feed dp_l)
        #pragma unroll
        for (int o = 0; o < 10; ++o) {
            const float* wr = pdp_w1 + (10 + o) * 276;
            float s = sacc[10 + o][q];
            #pragma unroll
            for (int i = 0; i < 10; ++i) s = fmaf(wr[256 + i], xu[i], s);
            #pragma unroll
            for (int i = 0; i < 10; ++i) s = fmaf(wr[266 + i], xl[i], s);
            tt[o] = fmaxf(s, 0.f);
        }
        float dpl[10];
        #pragma unroll
        for (int o = 0; o < 10; ++o) {
            float s = 0.f;
            #pragma unroll
            for (int i = 0; i < 10; ++i) s = fmaf(pdp_w2[(10 + o) * 10 + i], tt[i], s);
            dpl[o] = fmaxf(s, 0.f);
        }
        float su = sacc[20][q] + dU_ab[0];
        #pragma unroll
        for (int i = 0; i < 10; ++i) su = fmaf(dU_aw[256 + i], xv[i], su);
        #pragma unroll
        for (int i = 0; i < 10; ++i) su = fmaf(dU_aw[266 + i], xu[i], su);
        const float attU = sigm(su);
        float xfh[10];
        #pragma unroll
        for (int o = 0; o < 10; ++o) {
            float a = 0.f;
            #pragma unroll
            for (int i = 0; i < 10; ++i) a = fmaf(dU_w[o * 10 + i], xv[i], a);
            xfh[o] = fmaxf(attU * a, 0.f);
        }
        float msg[10];
        #pragma unroll
        for (int i = 0; i < 10; ++i) msg[i] = 0.f;
        #pragma unroll
        for (int pp = 0; pp < 4; ++pp) {
            const float* xq = xpg + (size_t)(pp * 8 + n) * 10 * HW + hw;
            float v[10];
            #pragma unroll
            for (int i = 0; i < 10; ++i) v[i] = xq[i * HW];
            float s = cU_ab[pp];
            #pragma unroll
            for (int i = 0; i < 10; ++i) s = fmaf(cU_aw[pp * 10 + i], v[i], s);
            float ca = sigm(s);
            #pragma unroll
            for (int i = 0; i < 10; ++i) msg[i] = fmaf(ca, v[i], msg[i]);
        }
        float m[10];
        #pragma unroll
        for (int o = 0; o < 10; ++o) {
            float s = 0.f;
            #pragma unroll
            for (int i = 0; i < 10; ++i) s = fmaf(cU_w[o * 20 + i],      xu[i],  s);
            #pragma unroll
            for (int i = 0; i < 10; ++i) s = fmaf(cU_w[o * 20 + 10 + i], msg[i], s);
            m[o] = fmaxf(s, 0.f) + fmaf(dpl[o], al, xu[o] * au) + xfh[o];
        }
        #pragma unroll
        for (int o = 0; o < 10; ++o) {
            float gs = uU_gb[o], cs = 0.f;
            #pragma unroll
            for (int i = 0; i < 10; ++i) {
                gs = fmaf(uU_gw[o * 20 + i], xu[i], gs);
                cs = fmaf(uU_cw[o * 20 + i], xu[i], cs);
            }
            #pragma unroll
            for (int i = 0; i < 10; ++i) {
                gs = fmaf(uU_gw[o * 20 + 10 + i], m[i], gs);
                cs = fmaf(uU_cw[o * 20 + 10 + i], m[i], cs);
            }
            float g = sigm(gs), cd = fmaxf(cs, 0.f);
            out[vb + o * HW] = xu[o] * (1.f - g) + cd * g;
        }
        out[2621440 + n * HW + hw] = attU;
    } else {
        // ------------------------------ L half ------------------------------
        float tt[10];                        // t rows 0..9 (feed dp_u)
        #pragma unroll
        for (int o = 0; o < 10; ++o) {
            const float* wr = pdp_w1 + o * 276;
            float s = sacc[o][q];
            #pragma unroll
            for (int i = 0; i < 10; ++i) s = fmaf(wr[256 + i], xu[i], s);
            #pragma unroll
            for (int i = 0; i < 10; ++i) s = fmaf(wr[266 + i], xl[i], s);
            tt[o] = fmaxf(s, 0.f);
        }
        float dpu[10];
        #pragma unroll
        for (int o = 0; o < 10; ++o) {
            float s = 0.f;
            #pragma unroll
            for (int i = 0; i < 10; ++i) s = fmaf(pdp_w2[o * 10 + i], tt[i], s);
            dpu[o] = fmaxf(s, 0.f);
        }
        float sl = sacc[21][q] + dL_ab[0];
        #pragma unroll
        for (int i = 0; i < 10; ++i) sl = fmaf(dL_aw[256 + i], xv[i], sl);
        #pragma unroll
        for (int i = 0; i < 10; ++i) sl = fmaf(dL_aw[266 + i], xl[i], sl);
        const float attL = sigm(sl);
        float xfh[10];
        #pragma unroll
        for (int o = 0; o < 10; ++o) {
            float a = 0.f;
            #pragma unroll
            for (int i = 0; i < 10; ++i) a = fmaf(dL_w[o * 10 + i], xv[i], a);
            xfh[o] = fmaxf(attL * a, 0.f);
        }
        float msg[10];
        #pragma unroll
        for (int i = 0; i < 10; ++i) msg[i] = 0.f;
        #pragma unroll
        for (int pp = 0; pp < 2; ++pp) {
            const float* xq = xpg + (size_t)((pp + 4) * 8 + n) * 10 * HW + hw;
            float v[10];
            #pragma unroll
            for (int i = 0; i < 10; ++i) v[i] = xq[i * HW];
            float s = cL_ab[pp];
            #pragma unroll
            for (int i = 0; i < 10; ++i) s = fmaf(cL_aw[pp * 10 + i], v[i], s);
            float ca = sigm(s);
            #pragma unroll
            for (int i = 0; i < 10; ++i) msg[i] = fmaf(ca, v[i], msg[i]);
        }
        float m[10];
        #pragma unroll
        for (int o = 0; o < 10; ++o) {
            float s = 0.f;
            #pragma unroll
            for (int i = 0; i < 10; ++i) s = fmaf(cL_w[o * 20 + i],      xl[i],  s);
            #pragma unroll
            for (int i = 0; i < 10; ++i) s = fmaf(cL_w[o * 20 + 10 + i], msg[i], s);
            m[o] = fmaxf(s, 0.f) + fmaf(dpu[o], au, xl[o] * al) + xfh[o];
        }
        #pragma unroll
        for (int o = 0; o < 10; ++o) {
            float gs = uL_gb[o], cs = 0.f;
            #pragma unroll
            for (int i = 0; i < 10; ++i) {
                gs = fmaf(uL_gw[o * 20 + i], xl[i], gs);
                cs = fmaf(uL_cw[o * 20 + i], xl[i], cs);
            }
            #pragma unroll
            for (int i = 0; i < 10; ++i) {
                gs = fmaf(uL_gw[o * 20 + 10 + i], m[i], gs);
                cs = fmaf(uL_cw[o * 20 + 10 + i], m[i], cs);
            }
            float g = sigm(gs), cd = fmaxf(cs, 0.f);
            out[1310720 + vb + o * HW] = xl[o] * (1.f - g) + cd * g;
        }
        out[2752512 + n * HW + hw] = attL;
    }
}

extern "C" void kernel_launch(void* const* d_in, const int* in_sizes, int n_in,
                              void* d_out, int out_size, void* d_ws, size_t ws_size,
                              hipStream_t stream) {
    (void)in_sizes; (void)n_in; (void)out_size; (void)ws_size;
    const float* hf   = (const float*)d_in[0];
    const float* xhu  = (const float*)d_in[1];
    const float* xhl  = (const float*)d_in[2];
    const float* xfg  = (const float*)d_in[3];
    const float* xpg  = (const float*)d_in[4];
    const float* w1   = (const float*)d_in[5];
    const float* w2   = (const float*)d_in[6];
    const float* aw   = (const float*)d_in[7];
    const float* ab   = (const float*)d_in[8];
    const float* cUaw = (const float*)d_in[9];
    const float* cUab = (const float*)d_in[10];
    const float* cUw  = (const float*)d_in[11];
    const float* cLaw = (const float*)d_in[12];
    const float* cLab = (const float*)d_in[13];
    const float* cLw  = (const float*)d_in[14];
    const float* dUaw = (const float*)d_in[15];
    const float* dUab = (const float*)d_in[16];
    const float* dUw  = (const float*)d_in[17];
    const float* dLaw = (const float*)d_in[18];
    const float* dLab = (const float*)d_in[19];
    const float* dLw  = (const float*)d_in[20];
    const float* uUgw = (const float*)d_in[21];
    const float* uUgb = (const float*)d_in[22];
    const float* uUcw = (const float*)d_in[23];
    const float* uLgw = (const float*)d_in[24];
    const float* uLgb = (const float*)d_in[25];
    const float* uLcw = (const float*)d_in[26];

    _Float16* apack = (_Float16*)d_ws;       // 32 KB: [16][64][8] hi + lo

    hipLaunchKernelGGL(prep_apack, dim3(32), dim3(256), 0, stream,
                       w1, dUaw, dLaw, apack);
    hipLaunchKernelGGL(half_graph_fused, dim3(512), dim3(512), 0, stream,
        hf, xhu, xhl, xfg, xpg, w1, w2, aw, ab,
        cUaw, cUab, cUw, cLaw, cLab, cLw,
        dUaw, dUab, dUw, dLaw, dLab, dLw,
        uUgw, uUgb, uUcw, uLgw, uLgb, uLcw,
        (const _Float16*)apack,
        (float*)d_out);
}